// Round 2
// baseline (1920.940 us; speedup 1.0000x reference)
//
#include <hip/hip_runtime.h>

// GCN 2-layer: x[100000,128] @ W1[128,48] -> norm-scatter -> +b1, relu
//              -> @ W2[48,32] -> norm-scatter -> +b2
// Edge index arrives as int32 (harness converts), shape (2,E) flat: src then dst.

#define DIN1 128
#define DHID 48
#define DOUT 32

__global__ void deg_kernel(const int* __restrict__ dst, const float* __restrict__ ew,
                           float* __restrict__ deg, int E) {
    int e = blockIdx.x * blockDim.x + threadIdx.x;
    if (e < E) atomicAdd(&deg[dst[e]], ew[e]);
}

__global__ void dinv_kernel(float* __restrict__ deg_dinv, int n) {
    int i = blockIdx.x * blockDim.x + threadIdx.x;
    if (i < n) deg_dinv[i] = rsqrtf(deg_dinv[i] + 1.0f);  // deg >= 1 incl self-loop
}

// H[r][c] = sum_k relu?(X[r][k]) * W[k][c]; W row-major [DIN][DOUT_]
template <int DIN_, int DOUT_, int ROWS, bool RELU_IN>
__global__ __launch_bounds__(256) void gemm_kernel(const float* __restrict__ X,
                                                   const float* __restrict__ W,
                                                   float* __restrict__ H, int n) {
    __shared__ float sW[DIN_ * DOUT_];
    __shared__ float sX[ROWS * DIN_];
    const int tid = threadIdx.x;
    for (int i = tid; i < DIN_ * DOUT_; i += 256) sW[i] = W[i];
    const int row0 = blockIdx.x * ROWS;
    for (int i = tid; i < ROWS * DIN_; i += 256) {
        int r = row0 + i / DIN_;
        float v = (r < n) ? X[(size_t)r * DIN_ + (i % DIN_)] : 0.0f;
        if (RELU_IN) v = fmaxf(v, 0.0f);
        sX[i] = v;
    }
    __syncthreads();
    for (int o = tid; o < ROWS * DOUT_; o += 256) {
        int r = o / DOUT_;
        int c = o % DOUT_;
        if (row0 + r >= n) break;  // r is monotone in o
        float acc = 0.0f;
#pragma unroll 16
        for (int k = 0; k < DIN_; ++k) acc = fmaf(sX[r * DIN_ + k], sW[k * DOUT_ + c], acc);
        H[(size_t)(row0 + r) * DOUT_ + c] = acc;
    }
}

// out[i][:] = dinv[i]^2 * h[i][:] + b[:]   (self-loop term + bias, also inits accumulator)
template <int D>
__global__ void selfloop_init(const float* __restrict__ h, const float* __restrict__ dinv,
                              const float* __restrict__ b, float* __restrict__ out, int n) {
    constexpr int C = D / 4;
    int gid = blockIdx.x * blockDim.x + threadIdx.x;
    if (gid >= n * C) return;
    int r = gid / C;
    int c = gid % C;
    float di = dinv[r];
    float s = di * di;
    float4 hv = *reinterpret_cast<const float4*>(h + (size_t)r * D + c * 4);
    float4 bv = *reinterpret_cast<const float4*>(b + c * 4);
    float4 o;
    o.x = fmaf(s, hv.x, bv.x);
    o.y = fmaf(s, hv.y, bv.y);
    o.z = fmaf(s, hv.z, bv.z);
    o.w = fmaf(s, hv.w, bv.w);
    *reinterpret_cast<float4*>(out + (size_t)r * D + c * 4) = o;
}

// per (edge, 4-col chunk): out[dst] += dinv[src]*ew*dinv[dst] * h[src]
template <int D>
__global__ void scatter_kernel(const int* __restrict__ src, const int* __restrict__ dst,
                               const float* __restrict__ ew, const float* __restrict__ dinv,
                               const float* __restrict__ h, float* __restrict__ out,
                               int total) {
    constexpr int C = D / 4;
    int gid = blockIdx.x * blockDim.x + threadIdx.x;
    if (gid >= total) return;
    int e = gid / C;
    int c = gid % C;
    int s = src[e];
    int d = dst[e];
    float norm = dinv[s] * ew[e] * dinv[d];
    float4 hv = *reinterpret_cast<const float4*>(h + (size_t)s * D + c * 4);
    float* o = out + (size_t)d * D + c * 4;
    atomicAdd(o + 0, norm * hv.x);
    atomicAdd(o + 1, norm * hv.y);
    atomicAdd(o + 2, norm * hv.z);
    atomicAdd(o + 3, norm * hv.w);
}

extern "C" void kernel_launch(void* const* d_in, const int* in_sizes, int n_in,
                              void* d_out, int out_size, void* d_ws, size_t ws_size,
                              hipStream_t stream) {
    const float* x  = (const float*)d_in[0];
    const int*   ei = (const int*)d_in[1];
    const float* ew = (const float*)d_in[2];
    const float* W1 = (const float*)d_in[3];
    const float* b1 = (const float*)d_in[4];
    const float* W2 = (const float*)d_in[5];
    const float* b2 = (const float*)d_in[6];
    float* out = (float*)d_out;

    const int n = in_sizes[0] / DIN1;   // 100000
    const int E = in_sizes[1] / 2;      // 1600000
    const int* src = ei;
    const int* dst = ei + E;

    float* ws   = (float*)d_ws;
    float* dinv = ws;                   // n floats (deg then dinv in-place)
    float* h1   = dinv + n;             // n*48
    float* out1 = h1 + (size_t)n * DHID;   // n*48
    float* h2   = out1 + (size_t)n * DHID; // n*32

    hipMemsetAsync(dinv, 0, (size_t)n * sizeof(float), stream);
    deg_kernel<<<(E + 255) / 256, 256, 0, stream>>>(dst, ew, dinv, E);
    dinv_kernel<<<(n + 255) / 256, 256, 0, stream>>>(dinv, n);

    // ---- layer 1 ----
    gemm_kernel<DIN1, DHID, 32, false><<<(n + 31) / 32, 256, 0, stream>>>(x, W1, h1, n);
    {
        int tot = n * (DHID / 4);
        selfloop_init<DHID><<<(tot + 255) / 256, 256, 0, stream>>>(h1, dinv, b1, out1, n);
    }
    {
        int tot = E * (DHID / 4);  // 19.2M
        scatter_kernel<DHID><<<(tot + 255) / 256, 256, 0, stream>>>(src, dst, ew, dinv, h1, out1, tot);
    }

    // ---- layer 2 (relu fused into GEMM input load) ----
    gemm_kernel<DHID, DOUT, 32, true><<<(n + 31) / 32, 256, 0, stream>>>(out1, W2, h2, n);
    {
        int tot = n * (DOUT / 4);
        selfloop_init<DOUT><<<(tot + 255) / 256, 256, 0, stream>>>(h2, dinv, b2, out, n);
    }
    {
        int tot = E * (DOUT / 4);  // 12.8M
        scatter_kernel<DOUT><<<(tot + 255) / 256, 256, 0, stream>>>(src, dst, ew, dinv, h2, out, tot);
    }
}

// Round 3
// 557.696 us; speedup vs baseline: 3.4444x; 3.4444x over previous
//
#include <hip/hip_runtime.h>

// GCN 2-layer, CSR-based (no fp32 atomics in hot path):
//   build dst-CSR + per-edge norm once; per layer: GEMM -> per-node gather-aggregate.

#define DIN1 128
#define DHID 48
#define DOUT 32
#define SCAN_B 1024

// count[dst]++ ; deg[dst] += ew
__global__ void hist_kernel(const int* __restrict__ dst, const float* __restrict__ ew,
                            float* __restrict__ deg, int* __restrict__ count, int E) {
    int e = blockIdx.x * blockDim.x + threadIdx.x;
    if (e < E) {
        int d = dst[e];
        atomicAdd(&count[d], 1);
        atomicAdd(&deg[d], ew[e]);
    }
}

__global__ void dinv_kernel(float* __restrict__ deg_dinv, int n) {
    int i = blockIdx.x * blockDim.x + threadIdx.x;
    if (i < n) deg_dinv[i] = rsqrtf(deg_dinv[i] + 1.0f);  // +1 self-loop
}

// per-block inclusive scan -> exclusive per-element, block sums out
__global__ __launch_bounds__(SCAN_B) void scan1(const int* __restrict__ cnt,
                                                int* __restrict__ excl,
                                                int* __restrict__ bsums, int n) {
    __shared__ int s[SCAN_B];
    int i = blockIdx.x * SCAN_B + threadIdx.x;
    int v = (i < n) ? cnt[i] : 0;
    s[threadIdx.x] = v;
    __syncthreads();
    for (int off = 1; off < SCAN_B; off <<= 1) {
        int t = (threadIdx.x >= off) ? s[threadIdx.x - off] : 0;
        __syncthreads();
        s[threadIdx.x] += t;
        __syncthreads();
    }
    if (i < n) excl[i] = s[threadIdx.x] - v;
    if (threadIdx.x == SCAN_B - 1) bsums[blockIdx.x] = s[SCAN_B - 1];
}

// exclusive scan of block sums (nb <= SCAN_B), in place
__global__ __launch_bounds__(SCAN_B) void scan2(int* __restrict__ bsums, int nb) {
    __shared__ int s[SCAN_B];
    int v = (threadIdx.x < nb) ? bsums[threadIdx.x] : 0;
    s[threadIdx.x] = v;
    __syncthreads();
    for (int off = 1; off < SCAN_B; off <<= 1) {
        int t = (threadIdx.x >= off) ? s[threadIdx.x - off] : 0;
        __syncthreads();
        s[threadIdx.x] += t;
        __syncthreads();
    }
    if (threadIdx.x < nb) bsums[threadIdx.x] = s[threadIdx.x] - v;
}

// add block offsets; produce row_ptr and cursor copy; row_ptr[n] = E
__global__ __launch_bounds__(SCAN_B) void scan3(int* __restrict__ row_ptr,
                                                const int* __restrict__ bsums,
                                                int* __restrict__ cursor, int n, int E) {
    int i = blockIdx.x * SCAN_B + threadIdx.x;
    if (i < n) {
        int v = row_ptr[i] + bsums[blockIdx.x];
        row_ptr[i] = v;
        cursor[i] = v;
    }
    if (i == 0) row_ptr[n] = E;
}

// place edges sorted by dst; pack (src, norm) into int2
__global__ void reorder_kernel(const int* __restrict__ src, const int* __restrict__ dst,
                               const float* __restrict__ ew, const float* __restrict__ dinv,
                               int* __restrict__ cursor, int2* __restrict__ ep, int E) {
    int e = blockIdx.x * blockDim.x + threadIdx.x;
    if (e >= E) return;
    int s = src[e];
    int d = dst[e];
    float nm = dinv[s] * ew[e] * dinv[d];
    int pos = atomicAdd(&cursor[d], 1);
    ep[pos] = make_int2(s, __float_as_int(nm));
}

// H[r][c] = sum_k relu?(X[r][k]) * W[k][c]; W row-major [DIN][DOUT_]
template <int DIN_, int DOUT_, int ROWS, bool RELU_IN>
__global__ __launch_bounds__(256) void gemm_kernel(const float* __restrict__ X,
                                                   const float* __restrict__ W,
                                                   float* __restrict__ H, int n) {
    __shared__ float sW[DIN_ * DOUT_];
    __shared__ float sX[ROWS * DIN_];
    const int tid = threadIdx.x;
    for (int i = tid; i < DIN_ * DOUT_; i += 256) sW[i] = W[i];
    const int row0 = blockIdx.x * ROWS;
    for (int i = tid; i < ROWS * DIN_; i += 256) {
        int r = row0 + i / DIN_;
        float v = (r < n) ? X[(size_t)r * DIN_ + (i % DIN_)] : 0.0f;
        if (RELU_IN) v = fmaxf(v, 0.0f);
        sX[i] = v;
    }
    __syncthreads();
    for (int o = tid; o < ROWS * DOUT_; o += 256) {
        int r = o / DOUT_;
        int c = o % DOUT_;
        if (row0 + r >= n) break;  // r monotone in o
        float acc = 0.0f;
#pragma unroll 16
        for (int k = 0; k < DIN_; ++k) acc = fmaf(sX[r * DIN_ + k], sW[k * DOUT_ + c], acc);
        H[(size_t)(row0 + r) * DOUT_ + c] = acc;
    }
}

// out[i][c4] = b + dinv[i]^2*h[i][c4] + sum_{edges->i} norm * h[src][c4]
template <int D>
__global__ __launch_bounds__(256) void aggregate_kernel(const int* __restrict__ row_ptr,
                                                        const int2* __restrict__ ep,
                                                        const float* __restrict__ h,
                                                        const float* __restrict__ dinv,
                                                        const float* __restrict__ b,
                                                        float* __restrict__ out, int n) {
    constexpr int C = D / 4;
    int gid = blockIdx.x * blockDim.x + threadIdx.x;
    if (gid >= n * C) return;
    int i = gid / C;
    int c = gid % C;
    const float4* h4 = reinterpret_cast<const float4*>(h);
    float di = dinv[i];
    float sl = di * di;
    float4 acc = h4[(size_t)i * C + c];
    acc.x *= sl; acc.y *= sl; acc.z *= sl; acc.w *= sl;
    int r0 = row_ptr[i], r1 = row_ptr[i + 1];
    for (int k = r0; k < r1; ++k) {
        int2 p = ep[k];
        float nm = __int_as_float(p.y);
        float4 hv = h4[(size_t)p.x * C + c];
        acc.x = fmaf(nm, hv.x, acc.x);
        acc.y = fmaf(nm, hv.y, acc.y);
        acc.z = fmaf(nm, hv.z, acc.z);
        acc.w = fmaf(nm, hv.w, acc.w);
    }
    float4 bv = reinterpret_cast<const float4*>(b)[c];
    acc.x += bv.x; acc.y += bv.y; acc.z += bv.z; acc.w += bv.w;
    reinterpret_cast<float4*>(out)[(size_t)i * C + c] = acc;
}

extern "C" void kernel_launch(void* const* d_in, const int* in_sizes, int n_in,
                              void* d_out, int out_size, void* d_ws, size_t ws_size,
                              hipStream_t stream) {
    const float* x  = (const float*)d_in[0];
    const int*   ei = (const int*)d_in[1];
    const float* ew = (const float*)d_in[2];
    const float* W1 = (const float*)d_in[3];
    const float* b1 = (const float*)d_in[4];
    const float* W2 = (const float*)d_in[5];
    const float* b2 = (const float*)d_in[6];
    float* out = (float*)d_out;

    const int n = in_sizes[0] / DIN1;   // 100000
    const int E = in_sizes[1] / 2;      // 1600000
    const int* src = ei;
    const int* dst = ei + E;

    // workspace layout (floats; keep 16B alignment for float4 regions)
    float* ws      = (float*)d_ws;
    float* dinv    = ws;                       // n   (deg then dinv in place)
    int*   count   = (int*)(ws + n);           // n
    int*   row_ptr = count + n;                // n+4 (padded)
    int*   bsums   = row_ptr + n + 4;          // SCAN_B
    int*   cursor  = bsums + SCAN_B;           // n
    int2*  ep      = (int2*)(cursor + n);      // E (8B each)
    float* h1      = (float*)(ep + E);         // n*48
    float* out1    = h1 + (size_t)n * DHID;    // n*48
    float* h2      = out1 + (size_t)n * DHID;  // n*32

    const int nb = (n + SCAN_B - 1) / SCAN_B;  // 98

    // deg + count zero (adjacent)
    hipMemsetAsync(ws, 0, (size_t)2 * n * sizeof(float), stream);
    hist_kernel<<<(E + 255) / 256, 256, 0, stream>>>(dst, ew, dinv, count, E);
    dinv_kernel<<<(n + 255) / 256, 256, 0, stream>>>(dinv, n);

    // exclusive scan count -> row_ptr (+cursor copy)
    scan1<<<nb, SCAN_B, 0, stream>>>(count, row_ptr, bsums, n);
    scan2<<<1, SCAN_B, 0, stream>>>(bsums, nb);
    scan3<<<nb, SCAN_B, 0, stream>>>(row_ptr, bsums, cursor, n, E);

    // sort edges by dst, pack (src, norm)
    reorder_kernel<<<(E + 255) / 256, 256, 0, stream>>>(src, dst, ew, dinv, cursor, ep, E);

    // ---- layer 1 ----
    gemm_kernel<DIN1, DHID, 32, false><<<(n + 31) / 32, 256, 0, stream>>>(x, W1, h1, n);
    aggregate_kernel<DHID><<<(n * (DHID / 4) + 255) / 256, 256, 0, stream>>>(
        row_ptr, ep, h1, dinv, b1, out1, n);

    // ---- layer 2 (relu fused into GEMM input load) ----
    gemm_kernel<DHID, DOUT, 32, true><<<(n + 31) / 32, 256, 0, stream>>>(out1, W2, h2, n);
    aggregate_kernel<DOUT><<<(n * (DOUT / 4) + 255) / 256, 256, 0, stream>>>(
        row_ptr, ep, h2, dinv, b2, out, n);
}

// Round 4
// 477.239 us; speedup vs baseline: 4.0251x; 1.1686x over previous
//
#include <hip/hip_runtime.h>

// GCN 2-layer, CSR-based, atomic-minimized:
//   hist: ONE u64 atomic per edge packs (count<<40 | fixpoint32(ew))
//   alloc: fused dinv + segment allocation (block scan + 1 atomic/block)
//   reorder: counting-sort placement, packs (src, norm)
//   per layer: GEMM (LDS, float4-staged) -> per-node gather aggregate (no atomics)

#define DIN1 128
#define DHID 48
#define DOUT 32
#define MASK40 ((1ull << 40) - 1)

__global__ void hist64_kernel(const int* __restrict__ dst, const float* __restrict__ ew,
                              unsigned long long* __restrict__ packed, int E) {
    int e = blockIdx.x * blockDim.x + threadIdx.x;
    if (e < E) {
        unsigned long long add =
            (1ull << 40) | (unsigned long long)((double)ew[e] * 4294967296.0);
        atomicAdd(&packed[dst[e]], add);
    }
}

// decode packed -> dinv, count; allocate contiguous per-node segment via block scan + gcur
__global__ __launch_bounds__(256) void alloc_kernel(const unsigned long long* __restrict__ packed,
                                                    float* __restrict__ dinv,
                                                    int* __restrict__ row_start,
                                                    int* __restrict__ cursor,
                                                    int* __restrict__ count,
                                                    int* __restrict__ gcur, int n) {
    __shared__ int s[256];
    __shared__ int sbase;
    const int tid = threadIdx.x;
    const int i = blockIdx.x * 256 + tid;
    int c = 0;
    if (i < n) {
        unsigned long long v = packed[i];
        c = (int)(v >> 40);
        float deg = (float)((double)(v & MASK40) * (1.0 / 4294967296.0));
        dinv[i] = rsqrtf(deg + 1.0f);  // +1 self-loop
        count[i] = c;
    }
    s[tid] = c;
    __syncthreads();
    for (int off = 1; off < 256; off <<= 1) {  // Hillis-Steele inclusive scan
        int t = (tid >= off) ? s[tid - off] : 0;
        __syncthreads();
        s[tid] += t;
        __syncthreads();
    }
    if (tid == 255) sbase = atomicAdd(gcur, s[255]);
    __syncthreads();
    if (i < n) {
        int st = sbase + s[tid] - c;
        row_start[i] = st;
        cursor[i] = st;
    }
}

// place edges grouped by dst; pack (src, norm) into int2
__global__ void reorder_kernel(const int* __restrict__ src, const int* __restrict__ dst,
                               const float* __restrict__ ew, const float* __restrict__ dinv,
                               int* __restrict__ cursor, int2* __restrict__ ep, int E) {
    int e = blockIdx.x * blockDim.x + threadIdx.x;
    if (e >= E) return;
    int s = src[e];
    int d = dst[e];
    float nm = dinv[s] * ew[e] * dinv[d];
    int pos = atomicAdd(&cursor[d], 1);
    ep[pos] = make_int2(s, __float_as_int(nm));
}

// H[r][c] = sum_k relu?(X[r][k]) * W[k][c]; W row-major [DIN][DOUT_]
template <int DIN_, int DOUT_, int ROWS, bool RELU_IN>
__global__ __launch_bounds__(256) void gemm_kernel(const float* __restrict__ X,
                                                   const float* __restrict__ W,
                                                   float* __restrict__ H, int n) {
    __shared__ float sW[DIN_ * DOUT_];
    __shared__ float sX[ROWS * DIN_];
    const int tid = threadIdx.x;
    const float4* W4 = reinterpret_cast<const float4*>(W);
    for (int i = tid; i < DIN_ * DOUT_ / 4; i += 256)
        reinterpret_cast<float4*>(sW)[i] = W4[i];
    const int row0 = blockIdx.x * ROWS;
    const float4* X4 = reinterpret_cast<const float4*>(X);
    constexpr int C4 = DIN_ / 4;
    for (int i = tid; i < ROWS * C4; i += 256) {
        int r = row0 + i / C4;
        float4 v = make_float4(0.f, 0.f, 0.f, 0.f);
        if (r < n) v = X4[(size_t)r * C4 + (i % C4)];
        if (RELU_IN) {
            v.x = fmaxf(v.x, 0.f); v.y = fmaxf(v.y, 0.f);
            v.z = fmaxf(v.z, 0.f); v.w = fmaxf(v.w, 0.f);
        }
        reinterpret_cast<float4*>(sX)[i] = v;
    }
    __syncthreads();
    for (int o = tid; o < ROWS * DOUT_; o += 256) {
        int r = o / DOUT_;
        int c = o % DOUT_;
        if (row0 + r >= n) break;  // r monotone in o
        float acc = 0.0f;
#pragma unroll 16
        for (int k = 0; k < DIN_; ++k) acc = fmaf(sX[r * DIN_ + k], sW[k * DOUT_ + c], acc);
        H[(size_t)(row0 + r) * DOUT_ + c] = acc;
    }
}

// out[i][c4] = b + dinv[i]^2*h[i][c4] + sum_{edges->i} norm * h[src][c4]
template <int D>
__global__ __launch_bounds__(256) void aggregate_kernel(const int* __restrict__ row_start,
                                                        const int* __restrict__ count,
                                                        const int2* __restrict__ ep,
                                                        const float* __restrict__ h,
                                                        const float* __restrict__ dinv,
                                                        const float* __restrict__ b,
                                                        float* __restrict__ out, int n) {
    constexpr int C = D / 4;
    int gid = blockIdx.x * blockDim.x + threadIdx.x;
    if (gid >= n * C) return;
    int i = gid / C;
    int c = gid % C;
    const float4* h4 = reinterpret_cast<const float4*>(h);
    float di = dinv[i];
    float sl = di * di;
    float4 acc = h4[(size_t)i * C + c];
    acc.x *= sl; acc.y *= sl; acc.z *= sl; acc.w *= sl;
    int r0 = row_start[i], r1 = r0 + count[i];
    for (int k = r0; k < r1; ++k) {
        int2 p = ep[k];
        float nm = __int_as_float(p.y);
        float4 hv = h4[(size_t)p.x * C + c];
        acc.x = fmaf(nm, hv.x, acc.x);
        acc.y = fmaf(nm, hv.y, acc.y);
        acc.z = fmaf(nm, hv.z, acc.z);
        acc.w = fmaf(nm, hv.w, acc.w);
    }
    float4 bv = reinterpret_cast<const float4*>(b)[c];
    acc.x += bv.x; acc.y += bv.y; acc.z += bv.z; acc.w += bv.w;
    reinterpret_cast<float4*>(out)[(size_t)i * C + c] = acc;
}

extern "C" void kernel_launch(void* const* d_in, const int* in_sizes, int n_in,
                              void* d_out, int out_size, void* d_ws, size_t ws_size,
                              hipStream_t stream) {
    const float* x  = (const float*)d_in[0];
    const int*   ei = (const int*)d_in[1];
    const float* ew = (const float*)d_in[2];
    const float* W1 = (const float*)d_in[3];
    const float* b1 = (const float*)d_in[4];
    const float* W2 = (const float*)d_in[5];
    const float* b2 = (const float*)d_in[6];
    float* out = (float*)d_out;

    const int n = in_sizes[0] / DIN1;   // 100000
    const int E = in_sizes[1] / 2;      // 1600000
    const int* src = ei;
    const int* dst = ei + E;

    // workspace layout (16B-aligned chunks; n*8 and n*4 are multiples of 16)
    char* w = (char*)d_ws;
    unsigned long long* packed = (unsigned long long*)w;  w += (size_t)n * 8;  // zeroed
    int*   gcur      = (int*)w;                           w += 16;             // zeroed
    float* dinv      = (float*)w;                         w += (size_t)n * 4;
    int*   row_start = (int*)w;                           w += (size_t)n * 4;
    int*   cursor    = (int*)w;                           w += (size_t)n * 4;
    int*   count     = (int*)w;                           w += (size_t)n * 4;
    int2*  ep        = (int2*)w;                          w += (size_t)E * 8;
    float* h1        = (float*)w;                         w += (size_t)n * DHID * 4;
    float* out1      = (float*)w;                         w += (size_t)n * DHID * 4;
    float* h2        = (float*)w;

    hipMemsetAsync(packed, 0, (size_t)n * 8 + 16, stream);  // packed + gcur

    hist64_kernel<<<(E + 255) / 256, 256, 0, stream>>>(dst, ew, packed, E);
    alloc_kernel<<<(n + 255) / 256, 256, 0, stream>>>(packed, dinv, row_start, cursor, count,
                                                      gcur, n);
    reorder_kernel<<<(E + 255) / 256, 256, 0, stream>>>(src, dst, ew, dinv, cursor, ep, E);

    // ---- layer 1 ----
    gemm_kernel<DIN1, DHID, 32, false><<<(n + 31) / 32, 256, 0, stream>>>(x, W1, h1, n);
    aggregate_kernel<DHID><<<(n * (DHID / 4) + 255) / 256, 256, 0, stream>>>(
        row_start, count, ep, h1, dinv, b1, out1, n);

    // ---- layer 2 (relu fused into GEMM input load) ----
    gemm_kernel<DHID, DOUT, 32, true><<<(n + 31) / 32, 256, 0, stream>>>(out1, W2, h2, n);
    aggregate_kernel<DOUT><<<(n * (DOUT / 4) + 255) / 256, 256, 0, stream>>>(
        row_start, count, ep, h2, dinv, b2, out, n);
}